// Round 4
// baseline (466.390 us; speedup 1.0000x reference)
//
#include <hip/hip_runtime.h>
#include <stdint.h>

#define NN 8192
#define CC 128
#define BN_EPS 1e-5f

__device__ inline unsigned short f2bf(float f) {
    unsigned int u = __float_as_uint(f);
    unsigned int r = (u + 0x7fffu + ((u >> 16) & 1u)) >> 16;   // RNE
    return (unsigned short)r;
}

// ---------------------------------------------------------------------------
// Kernel 1a: stream A row-major (contiguous!) -> row-major bitmask + degrees.
//   M[j*128 + w] : u64, bit l set iff A[j][col(w,l)] != 0,
//                  col(w,l) = 256*(w>>2) + 4*l + (w&3)   (ballot bit order)
//   deg[j]       : rowsum of A[j,:] (scalar popcount, no atomics)
// One wave per row j: 32 iters x uint4/lane = 1 KB/instr, 32 KB linear.
// Iter t ballots cols 256t+4l+q (q=0..3) -> words 4t..4t+3; lane 2t keeps
// (b0,b1), lane 2t+1 keeps (b2,b3) -> single coalesced ulonglong2 store.
// ---------------------------------------------------------------------------
__global__ __launch_bounds__(256, 8) void k1a_rowmask(
        const float* __restrict__ A, unsigned long long* __restrict__ M,
        float* __restrict__ deg) {
    const int lane = threadIdx.x & 63;
    const int wave = threadIdx.x >> 6;
    const int j = blockIdx.x * 4 + wave;

    const uint4* Ap = reinterpret_cast<const uint4*>(A + (size_t)j * NN) + lane;
    unsigned long long m0 = 0, m1 = 0;
    int degc = 0;

    #pragma unroll 4
    for (int t = 0; t < 32; ++t) {
        uint4 v = Ap[t * 64];                   // cols 256t + 4*lane + q
        unsigned long long b0 = __ballot(v.x != 0u);
        unsigned long long b1 = __ballot(v.y != 0u);
        unsigned long long b2 = __ballot(v.z != 0u);
        unsigned long long b3 = __ballot(v.w != 0u);
        degc += __popcll(b0) + __popcll(b1) + __popcll(b2) + __popcll(b3);
        if (lane == 2 * t)     { m0 = b0; m1 = b1; }   // words 4t, 4t+1
        if (lane == 2 * t + 1) { m0 = b2; m1 = b3; }   // words 4t+2, 4t+3
    }

    unsigned long long* p = M + (size_t)j * 128 + 2 * lane;
    *reinterpret_cast<ulonglong2*>(p) = make_ulonglong2(m0, m1);
    if (lane == 0) deg[j] = (float)degc;
}

// ---------------------------------------------------------------------------
// Kernel 1b: 64x64 bit-block transpose  M[j][w] -> Mt[J*8192 + w*64 + l].
// One wave per (J, w): lane r loads M[64J+r][w]; 64 ballots produce the
// transposed words (bit r of tw_l = bit l of W_r); lane l keeps tw_l.
// Stores coalesced (512 B/wave). 16 MB total traffic, L3-resident.
// Column semantics carried entirely by k1c's index permutation.
// ---------------------------------------------------------------------------
__global__ __launch_bounds__(256, 8) void k1b_transpose(
        const unsigned long long* __restrict__ M,
        unsigned long long* __restrict__ Mt) {
    const int lane = threadIdx.x & 63;
    const int wave = threadIdx.x >> 6;
    const int task = blockIdx.x * 4 + wave;     // 0..16383
    const int J = task >> 7;                    // j-band 0..127
    const int w = task & 127;                   // word-col 0..127

    unsigned long long W = M[(size_t)(J * 64 + lane) * 128 + w];
    unsigned int Wlo = (unsigned int)W, Whi = (unsigned int)(W >> 32);
    unsigned long long keep = 0;

    #pragma unroll 8
    for (int l = 0; l < 64; ++l) {
        unsigned int bit = (l < 32) ? ((Wlo >> l) & 1u) : ((Whi >> (l - 32)) & 1u);
        unsigned long long tw = __ballot(bit != 0u);
        if (lane == l) keep = tw;
    }
    Mt[(size_t)J * NN + w * 64 + lane] = keep;
}

// ---------------------------------------------------------------------------
// Kernel 1c: aggN[i,:] = (1/deg[i]) * sum_{j : A[j,i]!=0} X[j,:]
// One BLOCK per output row i; 4 waves split the 128 bands, LDS reduce.
// Only change vs prev round: block-uniform permuted index pi(i) undoing the
// ballot column order:  i -> (w = 4*(i>>8)+(i&3), l = (i&255)>>2).
// ---------------------------------------------------------------------------
__global__ __launch_bounds__(256, 8) void k1c_gather(
        const unsigned long long* __restrict__ Mt, const float* __restrict__ X,
        const float* __restrict__ deg, float* __restrict__ aggN) {
    __shared__ float red[4][128];
    const int lane = threadIdx.x & 63;
    const int wave = threadIdx.x >> 6;
    const int i = blockIdx.x;
    const int pi = (4 * (i >> 8) + (i & 3)) * 64 + ((i & 255) >> 2);

    unsigned long long w = 0;
    if (lane < 32)
        w = Mt[(size_t)(wave * 32 + lane) * NN + pi];
    float acc0 = 0.0f, acc1 = 0.0f;

    unsigned long long any = __ballot(w != 0ull);   // bits only in lanes 0..31
    while (any) {
        int q = __builtin_ctzll(any); any &= any - 1;
        unsigned long long u = __shfl(w, q);
        const float* Xq = X + (size_t)((wave * 32 + q) * 64) * CC;
        while (u) {
            int b = __builtin_ctzll(u); u &= u - 1;
            const float* xr = Xq + b * CC;
            acc0 += xr[lane];
            acc1 += xr[64 + lane];
        }
    }

    red[wave][lane]      = acc0;
    red[wave][64 + lane] = acc1;
    __syncthreads();
    if (wave == 0) {
        float s0 = red[0][lane]      + red[1][lane]      + red[2][lane]      + red[3][lane];
        float s1 = red[0][64 + lane] + red[1][64 + lane] + red[2][64 + lane] + red[3][64 + lane];
        float d  = deg[i];
        float rd = (d == 0.0f) ? 1.0f : (1.0f / d);
        aggN[(size_t)i * CC + lane]      = s0 * rd;
        aggN[(size_t)i * CC + 64 + lane] = s1 * rd;
    }
}

// ---------------------------------------------------------------------------
// Kernel 2: h = aggN @ Wn^T + X @ Wc^T + bn + bc, fused BN partial sums.
// Fused LDS array Wp[swz(k*128+c)] = bf16(Wn)|bf16(Wc)<<16, XOR swizzle
// ^(k&31): conflict-free reads, one ds_read_b32 per (k, both weights).
// (unchanged from prev round — verified -13.7 us)
// ---------------------------------------------------------------------------
__global__ __launch_bounds__(256, 2) void k2_gemm(
        const float* __restrict__ aggN, const float* __restrict__ X,
        const float* __restrict__ Wn, const float* __restrict__ bn,
        const float* __restrict__ Wc, const float* __restrict__ bc,
        float* __restrict__ h, float* __restrict__ bsum, float* __restrict__ bsq) {
    __shared__ unsigned int Wp[128 * 128];      // 64 KB -> 2 blocks/CU
    const int tid = threadIdx.x;
    for (int idx = tid * 4; idx < 128 * 128; idx += 1024) {
        float4 wn4 = *reinterpret_cast<const float4*>(Wn + idx);
        float4 wc4 = *reinterpret_cast<const float4*>(Wc + idx);
        int c = idx >> 7, k0 = idx & 127;       // 4 consecutive k, same c
        #pragma unroll
        for (int q = 0; q < 4; ++q) {
            unsigned int pk = (unsigned int)f2bf((&wn4.x)[q])
                            | ((unsigned int)f2bf((&wc4.x)[q]) << 16);
            int k = k0 + q;
            Wp[(k * 128 + c) ^ (k & 31)] = pk;
        }
    }
    __syncthreads();
    const int c  = tid & 127;
    const int rg = tid >> 7;
    const int i0 = blockIdx.x * 16 + rg * 8;

    float accN[8], accC[8];
    #pragma unroll
    for (int r = 0; r < 8; ++r) { accN[r] = 0.0f; accC[r] = 0.0f; }

    float4 ar[8], xr[8], an[8], xn[8];

#define LOADK(ab_, xb_, k_) do {                                               \
    _Pragma("unroll")                                                          \
    for (int r = 0; r < 8; ++r) {                                              \
        ab_[r] = *reinterpret_cast<const float4*>(&aggN[(size_t)(i0 + r) * CC + (k_)]); \
        xb_[r] = *reinterpret_cast<const float4*>(&X[(size_t)(i0 + r) * CC + (k_)]);    \
    }                                                                          \
} while (0)

#define COMPK(ab_, xb_, k_) do {                                               \
    _Pragma("unroll")                                                          \
    for (int kk = 0; kk < 4; ++kk) {                                           \
        int kq_ = (k_) + kk;                                                   \
        unsigned int pk_ = Wp[(kq_ * 128 + c) ^ (kq_ & 31)];                   \
        float wn_ = __uint_as_float(pk_ << 16);                                \
        float wc_ = __uint_as_float(pk_ & 0xffff0000u);                        \
        _Pragma("unroll")                                                      \
        for (int r = 0; r < 8; ++r) {                                          \
            accN[r] = fmaf((&ab_[r].x)[kk], wn_, accN[r]);                     \
            accC[r] = fmaf((&xb_[r].x)[kk], wc_, accC[r]);                     \
        }                                                                      \
    }                                                                          \
} while (0)

    LOADK(ar, xr, 0);
    for (int k = 0; k < 128; k += 8) {
        LOADK(an, xn, k + 4);
        COMPK(ar, xr, k);
        if (k + 8 < 128) LOADK(ar, xr, k + 8);
        COMPK(an, xn, k + 4);
    }

    const float bnc = bn[c], bcc = bc[c];
    float sp = 0.0f, sq = 0.0f;
    #pragma unroll
    for (int r = 0; r < 8; ++r) {
        float hv = accN[r] + accC[r] + bnc + bcc;
        h[(size_t)(i0 + r) * CC + c] = hv;
        sp += hv; sq += hv * hv;
    }
    __syncthreads();                              // Wp reads done; reuse as fp32 scratch
    float* red = reinterpret_cast<float*>(Wp);
    red[rg * 128 + c]       = sp;
    red[256 + rg * 128 + c] = sq;
    __syncthreads();
    if (rg == 0) {
        atomicAdd(&bsum[c], red[c] + red[128 + c]);
        atomicAdd(&bsq[c],  red[256 + c] + red[384 + c]);
    }
}

// ---------------------------------------------------------------------------
// Kernel 3: out = relu(gamma * (h - mu) * rsqrt(var + eps) + beta), float4.
// ---------------------------------------------------------------------------
__global__ __launch_bounds__(256) void k4_bn(
        const float* __restrict__ h, const float* __restrict__ bsum,
        const float* __restrict__ bsq, const float* __restrict__ gamma,
        const float* __restrict__ beta, float* __restrict__ out) {
    const int idx = (blockIdx.x * 256 + threadIdx.x) * 4;
    const int c0  = idx & 127;
    float4 hv = *reinterpret_cast<const float4*>(h + idx);
    float4 s4 = *reinterpret_cast<const float4*>(bsum + c0);
    float4 q4 = *reinterpret_cast<const float4*>(bsq + c0);
    float4 g4 = *reinterpret_cast<const float4*>(gamma + c0);
    float4 b4 = *reinterpret_cast<const float4*>(beta + c0);
    const float invN = 1.0f / 8192.0f;
    float4 o;
    const float* hp = &hv.x; const float* sp = &s4.x; const float* qp = &q4.x;
    const float* gp = &g4.x; const float* bp = &b4.x; float* op = &o.x;
    #pragma unroll
    for (int jj = 0; jj < 4; ++jj) {
        float mu  = sp[jj] * invN;
        float var = qp[jj] * invN - mu * mu;
        float sc  = gp[jj] * rsqrtf(var + BN_EPS);
        float v   = (hp[jj] - mu) * sc + bp[jj];
        op[jj] = v > 0.0f ? v : 0.0f;
    }
    *reinterpret_cast<float4*>(out + idx) = o;
}

extern "C" void kernel_launch(void* const* d_in, const int* in_sizes, int n_in,
                              void* d_out, int out_size, void* d_ws, size_t ws_size,
                              hipStream_t stream) {
    const float* X     = (const float*)d_in[0];   // [8192,128]
    const float* A     = (const float*)d_in[1];   // [8192,8192]
    const float* Wn    = (const float*)d_in[2];   // [128,128]
    const float* bn    = (const float*)d_in[3];
    const float* Wc    = (const float*)d_in[4];
    const float* bc    = (const float*)d_in[5];
    const float* gamma = (const float*)d_in[6];
    const float* beta  = (const float*)d_in[7];
    float* out = (float*)d_out;

    // Workspace layout (20.65 MB):
    //   deg   @ 0        (32 KB, fully written by k1a — no zeroing needed)
    //   bsum  @ 32768    (512 B, zeroed)
    //   bsq   @ 33280    (512 B, zeroed)
    //   aggN  @ 65536    (4 MB, fully written by k1c)
    //   M     @ 4259840  (8 MB, fully written by k1a; dead after k1b)
    //   Mt    @ 12648448 (8 MB, fully written by k1b)
    //   h     aliases M  (k2 writes h after k1b's last M read)
    char* ws = (char*)d_ws;
    float* deg  = (float*)(ws);
    float* bsum = (float*)(ws + 32768);
    float* bsq  = (float*)(ws + 33280);
    float* aggN = (float*)(ws + 65536);
    unsigned long long* M  = (unsigned long long*)(ws + 4259840);
    unsigned long long* Mt = (unsigned long long*)(ws + 12648448);
    float* h    = (float*)(ws + 4259840);

    hipMemsetAsync(ws + 32768, 0, 1024, stream);

    k1a_rowmask  <<<2048, 256, 0, stream>>>(A, M, deg);
    k1b_transpose<<<4096, 256, 0, stream>>>(M, Mt);
    k1c_gather   <<<8192, 256, 0, stream>>>(Mt, X, deg, aggN);
    k2_gemm      <<<512,  256, 0, stream>>>(aggN, X, Wn, bn, Wc, bc, h, bsum, bsq);
    k4_bn        <<<1024, 256, 0, stream>>>(h, bsum, bsq, gamma, beta, out);
}